// Round 9
// baseline (234.101 us; speedup 1.0000x reference)
//
#include <hip/hip_runtime.h>

// ---- problem constants ----
#define NIN 64
#define NOPS 1024
#define NB 2048
#define NNODES 1088            // NIN + NOPS
#define SLAB_SH 18             // node slot stride = 2048 rows * 128 B = 1<<18

// ---- workspace layout (bytes) ----
#define WS_SCHED 0u            // u64[1024] packed ops, sorted by (level, mat)
#define WS_LEV   8192u         // u32: [0]=nlev, [1]=slot of node 1087, [2]=err; +4096: u16 msta[2048]
#define WS_WT    16384u        // f16[8][64][128]  ([mat][n][k]), one-input mats zero-padded k>=64
#define WS_BIAS  147456u       // f32[512]
#define WS_NODES 163840u       // f16[cap][2048][64] slot slabs

// ---- k_main dynamic LDS layout (bytes) ----
#define LM_LINES 0u            // 2 levels x 64 lines x 1KB = 131072 (8 rows x 64 cols fp16, swizzled)
#define LM_SCHED 131072u       // u64[1024] = 8KB
#define LM_MSTA  139264u       // u16[2048] = 4KB
#define LM_TOTAL 143360u

typedef unsigned int u32;
typedef unsigned short u16;
typedef unsigned long long u64;
typedef _Float16 f16;
typedef _Float16 f16x8 __attribute__((ext_vector_type(8)));
typedef _Float16 f16x4 __attribute__((ext_vector_type(4)));
typedef float f32x4 __attribute__((ext_vector_type(4)));

#define MFMA16(a, b, c) __builtin_amdgcn_mfma_f32_16x16x32_f16((a), (b), (c), 0, 0, 0)

// sched word bits:
//  0-10 slot1 | 11-21 slot2 | 22-24 wx | 25-35 outslot
//  36-42 pos1, 43 fresh1 | 44-50 pos2, 51 fresh2 | 52-58 outpos, 59 ldsout | 60 globalout
//  61 pf1 (operand1 prefetch-safe: leaf or producer level <= L-2) | 62 pf2

// ---------------- schedule: levels + (level,mat) sort + liveness slots + edge classification ----------------
__global__ __launch_bounds__(1024) void k_sched(const int* __restrict__ wxv,
                                                const int* __restrict__ in1v,
                                                const int* __restrict__ in2v,
                                                char* __restrict__ ws, int cap) {
  __shared__ int s1[NOPS], s2[NOPS], sw[NOPS], slv[NOPS];
  __shared__ int lcnt[132];
  __shared__ int cnt2[1032];
  __shared__ u64 s_pack[NOPS];
  __shared__ int dl[NNODES], slot_of[NNODES], stk[NNODES];
  __shared__ int opPos[NOPS];
  __shared__ unsigned char needG[NOPS];
  __shared__ int s_flag, s_nlev, s_top, s_next;
  const int j = threadIdx.x;
  s1[j] = in1v[j]; s2[j] = in2v[j]; sw[j] = wxv[j]; slv[j] = 1;
  needG[j] = 0;
  if (j < 132) lcnt[j] = 0;
  if (j < 1032) cnt2[j] = 0;
  __syncthreads();
  for (int it = 0; it < NOPS + 1; ++it) {
    if (j == 0) s_flag = 0;
    __syncthreads();
    int p1 = s1[j];
    int l1 = (p1 >= NIN) ? slv[p1 - NIN] : 0;
    int l2 = 0;
    if (sw[j] >= 4) { int p2 = s2[j]; l2 = (p2 >= NIN) ? slv[p2 - NIN] : 0; }
    int nl = 1 + (l1 > l2 ? l1 : l2);
    if (nl != slv[j]) { slv[j] = nl; s_flag = 1; }
    __syncthreads();
    int f = s_flag;
    __syncthreads();
    if (!f) break;
  }
  if (j == 0) s_nlev = 0;
  __syncthreads();
  atomicMax(&s_nlev, slv[j]);
  __syncthreads();
  u32* wl = (u32*)(ws + WS_LEV);
  const int nlev = s_nlev;
  if (nlev > 127) { if (j == 0) { wl[0] = 0; wl[1] = 0; wl[2] = 1; } return; }
  atomicAdd(&lcnt[slv[j]], 1);
  atomicAdd(&cnt2[slv[j] * 8 + sw[j]], 1);
  __syncthreads();
  if (j == 0) {
    int acc = 0;
    for (int L = 1; L <= nlev; ++L) { int c = lcnt[L]; lcnt[L] = acc; acc += c; }
  }
  __syncthreads();
  int base = -1;
  if (j >= 8 && j < (nlev + 1) * 8) {
    int L = j >> 3, mm = j & 7;
    int s = lcnt[L];
    for (int q = 0; q < mm; ++q) s += cnt2[L * 8 + q];
    base = s;
  }
  u16* msta = (u16*)(ws + WS_LEV + 4096);
  for (int t = j; t < 2048; t += 1024) msta[t] = (u16)NOPS;
  __syncthreads();
  if (base >= 0) { cnt2[j] = base; msta[j] = (u16)base; }
  __syncthreads();
  { int slot = atomicAdd(&cnt2[slv[j] * 8 + sw[j]], 1);
    u64 p = (u64)(u32)s1[j] | ((u64)(u32)s2[j] << 11) | ((u64)(u32)sw[j] << 22) | ((u64)(u32)j << 25);
    s_pack[slot] = p;
    opPos[j] = slot - lcnt[slv[j]]; }
  __syncthreads();
  if (j == NOPS - 1) needG[j] = 1;
  { int L = slv[j];
    int i1n = s1[j];
    if (i1n >= NIN) { int p = i1n - NIN; if (!(slv[p] == L - 1 && opPos[p] < 64)) needG[p] = 1; }
    if (sw[j] >= 4) {
      int i2n = s2[j];
      if (i2n >= NIN) { int p = i2n - NIN; if (!(slv[p] == L - 1 && opPos[p] < 64)) needG[p] = 1; }
    } }
  for (int t = j; t < NNODES; t += 1024) dl[t] = (t < NIN) ? 0 : slv[t - NIN];
  __syncthreads();
  atomicMax(&dl[s1[j]], slv[j]);
  if (sw[j] >= 4) atomicMax(&dl[s2[j]], slv[j]);
  __syncthreads();
  if (j == 0) { dl[NNODES - 1] = nlev + 1; s_top = 0; s_next = NIN; }
  if (j < NIN) slot_of[j] = j;
  __syncthreads();
  for (int L = 1; L <= nlev; ++L) {
    for (int t = j; t < NNODES; t += 1024)
      if (dl[t] == L - 1) { int p = atomicAdd(&s_top, 1); stk[p] = slot_of[t]; }
    __syncthreads();
    if (slv[j] == L) {
      int p = atomicSub(&s_top, 1);
      int s;
      if (p >= 1) s = stk[p - 1]; else s = atomicAdd(&s_next, 1);
      slot_of[NIN + j] = s;
    }
    __syncthreads();
    if (j == 0 && s_top < 0) s_top = 0;
    __syncthreads();
  }
  {
    u64 m = s_pack[j];
    int i1n = (int)(m & 2047u), i2n = (int)((m >> 11) & 2047u);
    u32 wxn = (u32)((m >> 22) & 7u);
    int opn = (int)((m >> 25) & 2047u);
    int Lop = slv[opn];
    int two = (wxn >= 4);
    if (!two) i2n = i1n;
    u32 f1 = 0, p1 = 0, f2 = 0, p2 = 0;
    if (i1n >= NIN) { int p = i1n - NIN;
      if (slv[p] == Lop - 1 && opPos[p] < 64) { f1 = 1; p1 = (u32)opPos[p]; } }
    if (i2n >= NIN) { int p = i2n - NIN;
      if (slv[p] == Lop - 1 && opPos[p] < 64) { f2 = 1; p2 = (u32)opPos[p]; } }
    u32 pf1 = 1, pf2 = 1;   // leaf or producer <= Lop-2
    if (i1n >= NIN && slv[i1n - NIN] >= Lop - 1) pf1 = 0;
    if (i2n >= NIN && slv[i2n - NIN] >= Lop - 1) pf2 = 0;
    u32 op_pos = (u32)opPos[opn];
    u32 ldsout = (op_pos < 64) ? 1u : 0u;
    u32 gout   = needG[opn] ? 1u : 0u;
    u32 s1slot = (u32)slot_of[i1n];
    u32 s2slot = (u32)slot_of[i2n];
    u64 nm = (u64)s1slot | ((u64)s2slot << 11) | ((u64)wxn << 22)
           | ((u64)(u32)slot_of[NIN + opn] << 25)
           | ((u64)p1 << 36) | ((u64)f1 << 43)
           | ((u64)p2 << 44) | ((u64)f2 << 51)
           | ((u64)(op_pos & 63u) << 52) | ((u64)ldsout << 59)
           | ((u64)gout << 60) | ((u64)pf1 << 61) | ((u64)pf2 << 62);
    ((u64*)(ws + WS_SCHED))[j] = nm;
  }
  if (j == 0) {
    wl[0] = (u32)nlev;
    wl[1] = (u32)slot_of[NNODES - 1];
    wl[2] = (s_next > cap) ? 1u : 0u;
  }
}

// ---------------- weights: unify + zero-pad + transpose to [mat][n][k], fp16 ----------------
__global__ __launch_bounds__(256) void k_weights(const float* __restrict__ oW,
                                                 const float* __restrict__ ob,
                                                 const float* __restrict__ tW,
                                                 const float* __restrict__ tb,
                                                 char* __restrict__ ws) {
  f16* wt = (f16*)(ws + WS_WT);
  int t = blockIdx.x * 256 + threadIdx.x;
  #pragma unroll
  for (int q = 0; q < 4; ++q) {
    int e = t * 4 + q;                       // e = mat*8192 + n*128 + k
    int mat = e >> 13, n = (e >> 7) & 63, k = e & 127;
    float v;
    if (mat < 4) v = (k < 64) ? oW[mat * 4096 + k * 64 + n] : 0.f;
    else         v = tW[(mat - 4) * 8192 + k * 64 + n];
    wt[e] = (f16)v;
  }
  if (blockIdx.x == 0) {
    float* bs = (float*)(ws + WS_BIAS);
    for (int q = threadIdx.x; q < 512; q += 256)
      bs[q] = (q < 256) ? ob[q] : tb[q - 256];
  }
}

// ---------------- leaves: embedding gather -> slots 0..63 (fp16, vectorized) ----------------
__global__ __launch_bounds__(256) void k_leaves(const int* __restrict__ ids,
                                                const float* __restrict__ emb,
                                                char* __restrict__ ws) {
  int p = blockIdx.x * 256 + threadIdx.x;      // 131072 (i,b) pairs
  int i = p >> 11, b = p & 2047;
  int id = ids[b * 64 + i];
  const f32x4* src = (const f32x4*)(emb + (u32)id * 64u);
  f16x8* dst = (f16x8*)(ws + WS_NODES + ((u32)i << SLAB_SH) + (u32)b * 128u);
  #pragma unroll
  for (int q = 0; q < 8; ++q) {
    f32x4 lo = src[2 * q], hi = src[2 * q + 1];
    f16x8 v = { (f16)lo.x, (f16)lo.y, (f16)lo.z, (f16)lo.w,
                (f16)hi.x, (f16)hi.y, (f16)hi.z, (f16)hi.w };
    dst[q] = v;
  }
}

// ---------------- main: cross-barrier prefetch, counted vmcnt, raw s_barrier ----------------
struct PFT { f16x8 a0, a1, a2, a3; };

__global__ __launch_bounds__(1024, 4) void k_main(char* __restrict__ ws) {
  extern __shared__ char lds[];
  const int tid = threadIdx.x;
  const u32* wl = (const u32*)(ws + WS_LEV);
  if (wl[2]) return;               // uniform early-out before any barrier
  ((u64*)(lds + LM_SCHED))[tid] = ((const u64*)(ws + WS_SCHED))[tid];
  ((u32*)(lds + LM_MSTA))[tid] = ((const u32*)(ws + WS_LEV + 4096))[tid];
  const int nlev = (int)wl[0];

  const int lane = tid & 63;
  const int w   = tid >> 6;        // 16 waves
  const int m   = w & 7;           // owned weight matrix (m<4 => one-input)
  const int nh  = w >> 3;          // column half
  const int lhi = lane >> 4, llo = lane & 15;
  const int r0  = blockIdx.x * 8;  // 256 blocks x 8 batch rows
  char* nodes = ws + WS_NODES;

  // W cache: (32 cols x 128 k) slice of mat m; one-input waves only k<64 half
  const f16* wp = (const f16*)(ws + WS_WT) + m * 8192 + (nh * 32 + llo) * 128 + lhi * 8;
  const f16x8 W00 = *(const f16x8*)(wp +        0), W01 = *(const f16x8*)(wp +       32),
              W10 = *(const f16x8*)(wp + 2048 + 0), W11 = *(const f16x8*)(wp + 2048 + 32);
  f16x8 W02 = {}, W03 = {}, W12 = {}, W13 = {};
  if (m >= 4) {
    W02 = *(const f16x8*)(wp +       64); W03 = *(const f16x8*)(wp +       96);
    W12 = *(const f16x8*)(wp + 2048 + 64); W13 = *(const f16x8*)(wp + 2048 + 96);
  }
  const float* bsp = (const float*)(ws + WS_BIAS) + m * 64 + nh * 32 + lhi * 4;
  const f32x4 B0 = *(const f32x4*)(bsp), B1 = *(const f32x4*)(bsp + 16);
  __syncthreads();                 // staging visible; full drain OK (once)

  const u64* s_sched = (const u64*)(lds + LM_SCHED);
  const u16* s_msta  = (const u16*)(lds + LM_MSTA);

  const u32 a_off  = (u32)((r0 + (llo & 7)) * 128 + lhi * 16);
  const u32 st_off = (u32)((r0 + llo) * 128 + (nh * 32 + lhi * 4) * 2);
  const u32 swr    = (u32)((llo & 7) << 4);
  const u32 aL0    = (u32)((llo & 7) * 128 + ((lhi * 16)      ^ swr));
  const u32 aL1    = (u32)((llo & 7) * 128 + ((lhi * 16 + 64) ^ swr));
  const u32 stL0   = (u32)(llo * 128 + ((nh * 64 +      lhi * 8) ^ swr));
  const u32 stL1   = (u32)(llo * 128 + ((nh * 64 + 32 + lhi * 8) ^ swr));

  // ---- helpers ----
  auto pf2load = [&](PFT& P, u64 md) {       // always 4 global loads
    u32 i1 = (u32)md & 2047u;
    u32 i2 = ((u32)(md >> 11)) & 2047u;
    const char* b1 = nodes + ((u64)i1 << SLAB_SH) + a_off;
    P.a0 = *(const f16x8*)(b1);
    P.a1 = *(const f16x8*)(b1 + 64);
    const char* b2 = nodes + ((u64)i2 << SLAB_SH) + a_off;
    P.a2 = *(const f16x8*)(b2);
    P.a3 = *(const f16x8*)(b2 + 64);
  };
  auto pf1load = [&](PFT& P, u64 md) {       // always 2 global loads
    u32 i1 = (u32)md & 2047u;
    const char* b1 = nodes + ((u64)i1 << SLAB_SH) + a_off;
    P.a0 = *(const f16x8*)(b1);
    P.a1 = *(const f16x8*)(b1 + 64);
  };
  auto getop1 = [&](u64 md, u32 rb, const PFT& P, f16x8& x0, f16x8& x1) {
    if ((md >> 43) & 1) {                    // fresh: LDS line
      const char* l1 = lds + rb + (((u32)(md >> 36) & 127u) << 10);
      x0 = *(const f16x8*)(l1 + aL0);
      x1 = *(const f16x8*)(l1 + aL1);
    } else if (!((md >> 61) & 1)) {          // not prefetch-safe: on-demand global
      u32 i1 = (u32)md & 2047u;
      const char* b1 = nodes + ((u64)i1 << SLAB_SH) + a_off;
      x0 = *(const f16x8*)(b1);
      x1 = *(const f16x8*)(b1 + 64);
    } else { x0 = P.a0; x1 = P.a1; }         // prefetched
  };
  auto getop2 = [&](u64 md, u32 rb, const PFT& P, f16x8& x2, f16x8& x3) {
    if ((md >> 51) & 1) {
      const char* l2 = lds + rb + (((u32)(md >> 44) & 127u) << 10);
      x2 = *(const f16x8*)(l2 + aL0);
      x3 = *(const f16x8*)(l2 + aL1);
    } else if (!((md >> 62) & 1)) {
      u32 i2 = ((u32)(md >> 11)) & 2047u;
      const char* b2 = nodes + ((u64)i2 << SLAB_SH) + a_off;
      x2 = *(const f16x8*)(b2);
      x3 = *(const f16x8*)(b2 + 64);
    } else { x2 = P.a2; x3 = P.a3; }
  };
  auto getop1_od = [&](u64 md, u32 rb, f16x8& x0, f16x8& x1) {
    if ((md >> 43) & 1) {
      const char* l1 = lds + rb + (((u32)(md >> 36) & 127u) << 10);
      x0 = *(const f16x8*)(l1 + aL0);
      x1 = *(const f16x8*)(l1 + aL1);
    } else {
      u32 i1 = (u32)md & 2047u;
      const char* b1 = nodes + ((u64)i1 << SLAB_SH) + a_off;
      x0 = *(const f16x8*)(b1);
      x1 = *(const f16x8*)(b1 + 64);
    }
  };
  auto getop2_od = [&](u64 md, u32 rb, f16x8& x2, f16x8& x3) {
    if ((md >> 51) & 1) {
      const char* l2 = lds + rb + (((u32)(md >> 44) & 127u) << 10);
      x2 = *(const f16x8*)(l2 + aL0);
      x3 = *(const f16x8*)(l2 + aL1);
    } else {
      u32 i2 = ((u32)(md >> 11)) & 2047u;
      const char* b2 = nodes + ((u64)i2 << SLAB_SH) + a_off;
      x2 = *(const f16x8*)(b2);
      x3 = *(const f16x8*)(b2 + 64);
    }
  };
  auto storeR = [&](u64 md, u32 wb, f32x4 c0, f32x4 c1) {
    f16x4 r0v = { (f16)(c0.x > 0.f ? c0.x : 0.f), (f16)(c0.y > 0.f ? c0.y : 0.f),
                  (f16)(c0.z > 0.f ? c0.z : 0.f), (f16)(c0.w > 0.f ? c0.w : 0.f) };
    f16x4 r1v = { (f16)(c1.x > 0.f ? c1.x : 0.f), (f16)(c1.y > 0.f ? c1.y : 0.f),
                  (f16)(c1.z > 0.f ? c1.z : 0.f), (f16)(c1.w > 0.f ? c1.w : 0.f) };
    if (llo < 8) {
      if ((md >> 59) & 1) {
        char* lp = lds + wb + (((u32)(md >> 52) & 127u) << 10);
        *(f16x4*)(lp + stL0) = r0v;
        *(f16x4*)(lp + stL1) = r1v;
      }
      if ((md >> 60) & 1) {
        char* st = nodes + (((u64)((md >> 25) & 2047u)) << SLAB_SH) + st_off;
        *(f16x4*)(st)      = r0v;
        *(f16x4*)(st + 32) = r1v;
      }
    }
  };
  auto mfma8 = [&](f16x8 x0, f16x8 x1, f16x8 x2, f16x8 x3, f32x4& c0, f32x4& c1) {
    __builtin_amdgcn_s_setprio(1);
    c0 = MFMA16(W00, x0, c0); c0 = MFMA16(W01, x1, c0);
    c0 = MFMA16(W02, x2, c0); c0 = MFMA16(W03, x3, c0);
    c1 = MFMA16(W10, x0, c1); c1 = MFMA16(W11, x1, c1);
    c1 = MFMA16(W12, x2, c1); c1 = MFMA16(W13, x3, c1);
    __builtin_amdgcn_s_setprio(0);
  };
  auto mfma4 = [&](f16x8 x0, f16x8 x1, f32x4& c0, f32x4& c1) {
    __builtin_amdgcn_s_setprio(1);
    c0 = MFMA16(W00, x0, c0); c0 = MFMA16(W01, x1, c0);
    c1 = MFMA16(W10, x0, c1); c1 = MFMA16(W11, x1, c1);
    __builtin_amdgcn_s_setprio(0);
  };

  int k0 = (int)s_msta[8 + m];
  int k1 = (int)s_msta[8 + m + 1];
  k0 = __builtin_amdgcn_readfirstlane(k0);
  k1 = __builtin_amdgcn_readfirstlane(k1);

  u64 md0, md1, md2;
  PFT P0, P1, P2;
  {   // prologue prefetch for level 1
    int i0 = k0 < NOPS ? k0 : NOPS - 1;
    int ia = (k0 + 1 < k1) ? k0 + 1 : i0;
    int ib = (k0 + 2 < k1) ? k0 + 2 : i0;
    md0 = s_sched[i0]; md1 = s_sched[ia]; md2 = s_sched[ib];
    if (m < 4) { pf1load(P0, md0); pf1load(P1, md1); pf1load(P2, md2); }
    else       { pf2load(P0, md0); pf2load(P1, md1); pf2load(P2, md2); }
  }

  if (m < 4) {
    // ---------------- one-input waves: 4 MFMA, operand1 only ----------------
    for (int L = 1; L <= nlev; ++L) {
      const u32 rb = (u32)(((L - 1) & 1) << 16);
      const u32 wb = (u32)((L & 1) << 16);
      if (k0 < k1) {
        { f16x8 x0, x1; getop1(md0, rb, P0, x0, x1);
          f32x4 c0 = B0, c1 = B1; mfma4(x0, x1, c0, c1); storeR(md0, wb, c0, c1); }
        if (k0 + 1 < k1) { f16x8 x0, x1; getop1(md1, rb, P1, x0, x1);
          f32x4 c0 = B0, c1 = B1; mfma4(x0, x1, c0, c1); storeR(md1, wb, c0, c1); }
        if (k0 + 2 < k1) { f16x8 x0, x1; getop1(md2, rb, P2, x0, x1);
          f32x4 c0 = B0, c1 = B1; mfma4(x0, x1, c0, c1); storeR(md2, wb, c0, c1); }
        for (int k = k0 + 3; k < k1; ++k) {
          u64 md = s_sched[k];
          f16x8 x0, x1; getop1_od(md, rb, x0, x1);
          f32x4 c0 = B0, c1 = B1; mfma4(x0, x1, c0, c1); storeR(md, wb, c0, c1);
        }
      }
      int k0n = (int)s_msta[(L + 1) * 8 + m];
      int k1n = (int)s_msta[(L + 1) * 8 + m + 1];
      k0n = __builtin_amdgcn_readfirstlane(k0n);
      k1n = __builtin_amdgcn_readfirstlane(k1n);
      int i0 = k0n < NOPS ? k0n : NOPS - 1;
      int ia = (k0n + 1 < k1n) ? k0n + 1 : i0;
      int ib = (k0n + 2 < k1n) ? k0n + 2 : i0;
      md0 = s_sched[i0]; md1 = s_sched[ia]; md2 = s_sched[ib];
      pf1load(P0, md0); pf1load(P1, md1); pf1load(P2, md2);
      __builtin_amdgcn_sched_barrier(0);
      asm volatile("s_waitcnt vmcnt(6) lgkmcnt(0)");
      __builtin_amdgcn_sched_barrier(0);
      __builtin_amdgcn_s_barrier();
      __builtin_amdgcn_sched_barrier(0);
      k0 = k0n; k1 = k1n;
    }
  } else {
    // ---------------- two-input waves: 8 MFMA ----------------
    for (int L = 1; L <= nlev; ++L) {
      const u32 rb = (u32)(((L - 1) & 1) << 16);
      const u32 wb = (u32)((L & 1) << 16);
      if (k0 < k1) {
        { f16x8 x0, x1, x2, x3;
          getop1(md0, rb, P0, x0, x1); getop2(md0, rb, P0, x2, x3);
          f32x4 c0 = B0, c1 = B1; mfma8(x0, x1, x2, x3, c0, c1); storeR(md0, wb, c0, c1); }
        if (k0 + 1 < k1) { f16x8 x0, x1, x2, x3;
          getop1(md1, rb, P1, x0, x1); getop2(md1, rb, P1, x2, x3);
          f32x4 c0 = B0, c1 = B1; mfma8(x0, x1, x2, x3, c0, c1); storeR(md1, wb, c0, c1); }
        if (k0 + 2 < k1) { f16x8 x0, x1, x2, x3;
          getop1(md2, rb, P2, x0, x1); getop2(md2, rb, P2, x2, x3);
          f32x4 c0 = B0, c1 = B1; mfma8(x0, x1, x2, x3, c0, c1); storeR(md2, wb, c0, c1); }
        for (int k = k0 + 3; k < k1; ++k) {
          u64 md = s_sched[k];
          f16x8 x0, x1, x2, x3;
          getop1_od(md, rb, x0, x1); getop2_od(md, rb, x2, x3);
          f32x4 c0 = B0, c1 = B1; mfma8(x0, x1, x2, x3, c0, c1); storeR(md, wb, c0, c1);
        }
      }
      int k0n = (int)s_msta[(L + 1) * 8 + m];
      int k1n = (int)s_msta[(L + 1) * 8 + m + 1];
      k0n = __builtin_amdgcn_readfirstlane(k0n);
      k1n = __builtin_amdgcn_readfirstlane(k1n);
      int i0 = k0n < NOPS ? k0n : NOPS - 1;
      int ia = (k0n + 1 < k1n) ? k0n + 1 : i0;
      int ib = (k0n + 2 < k1n) ? k0n + 2 : i0;
      md0 = s_sched[i0]; md1 = s_sched[ia]; md2 = s_sched[ib];
      pf2load(P0, md0); pf2load(P1, md1); pf2load(P2, md2);
      __builtin_amdgcn_sched_barrier(0);
      asm volatile("s_waitcnt vmcnt(12) lgkmcnt(0)");
      __builtin_amdgcn_sched_barrier(0);
      __builtin_amdgcn_s_barrier();
      __builtin_amdgcn_sched_barrier(0);
      k0 = k0n; k1 = k1n;
    }
  }
}

// ---------------- final: out[b] = nodes[slot1087][b] . final_W + final_b ----------------
__global__ __launch_bounds__(256) void k_final(const float* __restrict__ fw,
                                               const float* __restrict__ fb,
                                               const char* __restrict__ ws,
                                               float* __restrict__ out) {
  __shared__ float s_fw[64];
  int t = threadIdx.x;
  if (t < 64) s_fw[t] = fw[t];
  __syncthreads();
  int b = blockIdx.x * 256 + t;
  const u32* wl = (const u32*)(ws + WS_LEV);
  if (wl[2]) { out[b] = 0.f; return; }
  u32 slot = wl[1];
  const f16x8* last = (const f16x8*)(ws + WS_NODES + ((u64)slot << SLAB_SH) + (u32)b * 128u);
  float acc = fb[0];
  #pragma unroll
  for (int q = 0; q < 8; ++q) {
    f16x8 v = last[q];
    #pragma unroll
    for (int e = 0; e < 8; ++e) acc += (float)v[e] * s_fw[q * 8 + e];
  }
  out[b] = acc;
}

extern "C" void kernel_launch(void* const* d_in, const int* in_sizes, int n_in,
                              void* d_out, int out_size, void* d_ws, size_t ws_size,
                              hipStream_t stream) {
  const int*   ids = (const int*)d_in[0];
  const int*   wx  = (const int*)d_in[1];
  const int*   i1  = (const int*)d_in[2];
  const int*   i2  = (const int*)d_in[3];
  const float* emb = (const float*)d_in[4];
  const float* oW  = (const float*)d_in[5];
  const float* ob  = (const float*)d_in[6];
  const float* tW  = (const float*)d_in[7];
  const float* tb  = (const float*)d_in[8];
  const float* fw  = (const float*)d_in[9];
  const float* fb  = (const float*)d_in[10];
  char* ws = (char*)d_ws;
  float* out = (float*)d_out;

  int cap = (int)((ws_size > (size_t)WS_NODES) ? ((ws_size - WS_NODES) >> SLAB_SH) : 0);
  if (cap < 80) return;
  if (cap > 2047) cap = 2047;

  hipLaunchKernelGGL(k_sched,   dim3(1),   dim3(1024), 0, stream, wx, i1, i2, ws, cap);
  hipLaunchKernelGGL(k_weights, dim3(64),  dim3(256),  0, stream, oW, ob, tW, tb, ws);
  hipLaunchKernelGGL(k_leaves,  dim3(512), dim3(256),  0, stream, ids, emb, ws);
  hipLaunchKernelGGL(k_main,    dim3(256), dim3(1024), LM_TOTAL, stream, ws);
  hipLaunchKernelGGL(k_final,   dim3(8),   dim3(256),  0, stream, fw, fb, ws, out);
}